// Round 1
// baseline (214.127 us; speedup 1.0000x reference)
//
#include <hip/hip_runtime.h>
#include <math.h>

// Problem constants
#define B_   8
#define L_   256
#define C_   512
#define OUT_ 512

// ---------------------------------------------------------------------------
// Kernel 1: fused relu-GEMM for both projections.
//   Y[m][n] = sum_k relu(X[m][k]) * W[k][n] + bias[n]
//   M = B*L = 2048, N = C = 512, K = C = 512.
// blockIdx.z = 0 -> pt = relu(xt)@Wp+bp ; z = 1 -> pc = relu(xd)@Wc+bc
// 64x64 output tile, KT=16, 256 threads, 4x4 microtile.
// ---------------------------------------------------------------------------
__global__ __launch_bounds__(256)
void proj_kernel(const float* __restrict__ xt, const float* __restrict__ Wp,
                 const float* __restrict__ bp,
                 const float* __restrict__ xd, const float* __restrict__ Wc,
                 const float* __restrict__ bc,
                 float* __restrict__ pt, float* __restrict__ pc)
{
    const int which = blockIdx.z;
    const float* __restrict__ X    = which ? xd : xt;
    const float* __restrict__ W    = which ? Wc : Wp;
    const float* __restrict__ bias = which ? bc : bp;
    float* __restrict__ Y          = which ? pc : pt;

    __shared__ float As[16][64];   // [k][m]
    __shared__ float Bs[16][64];   // [k][n]

    const int tid = threadIdx.x;
    const int tx = tid & 15, ty = tid >> 4;
    const int m0 = blockIdx.y * 64, n0 = blockIdx.x * 64;

    const int lm  = tid >> 2;         // 0..63   (A staging row)
    const int lk4 = (tid & 3) << 2;   // 0,4,8,12 (A staging k base)
    const int lk  = tid >> 4;         // 0..15   (B staging k)
    const int ln4 = (tid & 15) << 2;  // 0..60   (B staging n base)

    float acc[4][4] = {};

    for (int k0 = 0; k0 < C_; k0 += 16) {
        float4 av = *(const float4*)&X[(size_t)(m0 + lm) * C_ + k0 + lk4];
        As[lk4 + 0][lm] = fmaxf(av.x, 0.f);
        As[lk4 + 1][lm] = fmaxf(av.y, 0.f);
        As[lk4 + 2][lm] = fmaxf(av.z, 0.f);
        As[lk4 + 3][lm] = fmaxf(av.w, 0.f);
        float4 bv = *(const float4*)&W[(size_t)(k0 + lk) * C_ + n0 + ln4];
        *(float4*)&Bs[lk][ln4] = bv;
        __syncthreads();
        #pragma unroll
        for (int kk = 0; kk < 16; ++kk) {
            float4 a = *(const float4*)&As[kk][ty << 2];
            float4 b = *(const float4*)&Bs[kk][tx << 2];
            float ar[4] = {a.x, a.y, a.z, a.w};
            float br[4] = {b.x, b.y, b.z, b.w};
            #pragma unroll
            for (int i = 0; i < 4; ++i)
                #pragma unroll
                for (int j = 0; j < 4; ++j)
                    acc[i][j] = fmaf(ar[i], br[j], acc[i][j]);
        }
        __syncthreads();
    }
    #pragma unroll
    for (int i = 0; i < 4; ++i) {
        const int m = m0 + (ty << 2) + i;
        #pragma unroll
        for (int j = 0; j < 4; ++j) {
            const int n = n0 + (tx << 2) + j;
            Y[(size_t)m * C_ + n] = acc[i][j] + bias[n];
        }
    }
}

// ---------------------------------------------------------------------------
// Kernel 2: scores[b][i][j] = sigmoid( sum_c pt[b,i,c] * pc[b,j,c] )
// and per-batch total sum (atomicAdd into sums[b]).
// Per batch: 256x256 output, K=512. 64x64 tile, 256 threads, 4x4 microtile.
// grid = (4 n-tiles, 4 m-tiles, 8 batches)
// ---------------------------------------------------------------------------
__global__ __launch_bounds__(256)
void scores_kernel(const float* __restrict__ pt, const float* __restrict__ pc,
                   float* __restrict__ scores, float* __restrict__ sums)
{
    const int b = blockIdx.z;
    const float* __restrict__ A  = pt + (size_t)b * L_ * C_;
    const float* __restrict__ Bm = pc + (size_t)b * L_ * C_;

    __shared__ float As[16][64];   // [k][i]
    __shared__ float Bs[16][64];   // [k][j]
    __shared__ float red[256];

    const int tid = threadIdx.x;
    const int tx = tid & 15, ty = tid >> 4;
    const int m0 = blockIdx.y * 64, n0 = blockIdx.x * 64;

    const int lm  = tid >> 2;         // 0..63
    const int lk4 = (tid & 3) << 2;   // 0,4,8,12

    float acc[4][4] = {};

    for (int k0 = 0; k0 < C_; k0 += 16) {
        float4 av = *(const float4*)&A[(size_t)(m0 + lm) * C_ + k0 + lk4];
        As[lk4 + 0][lm] = av.x;
        As[lk4 + 1][lm] = av.y;
        As[lk4 + 2][lm] = av.z;
        As[lk4 + 3][lm] = av.w;
        float4 bv = *(const float4*)&Bm[(size_t)(n0 + lm) * C_ + k0 + lk4];
        Bs[lk4 + 0][lm] = bv.x;
        Bs[lk4 + 1][lm] = bv.y;
        Bs[lk4 + 2][lm] = bv.z;
        Bs[lk4 + 3][lm] = bv.w;
        __syncthreads();
        #pragma unroll
        for (int kk = 0; kk < 16; ++kk) {
            float4 a = *(const float4*)&As[kk][ty << 2];
            float4 b = *(const float4*)&Bs[kk][tx << 2];
            float ar[4] = {a.x, a.y, a.z, a.w};
            float br[4] = {b.x, b.y, b.z, b.w};
            #pragma unroll
            for (int i = 0; i < 4; ++i)
                #pragma unroll
                for (int j = 0; j < 4; ++j)
                    acc[i][j] = fmaf(ar[i], br[j], acc[i][j]);
        }
        __syncthreads();
    }

    float lsum = 0.f;
    #pragma unroll
    for (int i = 0; i < 4; ++i) {
        const int m = m0 + (ty << 2) + i;
        #pragma unroll
        for (int j = 0; j < 4; ++j) {
            const int n = n0 + (tx << 2) + j;
            const float d  = acc[i][j];
            const float sg = 1.0f / (1.0f + expf(-d));
            scores[(size_t)b * L_ * L_ + (size_t)m * L_ + n] = sg;
            lsum += sg;
        }
    }
    red[tid] = lsum;
    __syncthreads();
    for (int s = 128; s > 0; s >>= 1) {
        if (tid < s) red[tid] += red[tid + s];
        __syncthreads();
    }
    if (tid == 0) atomicAdd(&sums[b], red[0]);
}

// ---------------------------------------------------------------------------
// Kernel 3: the heavy one.
// partial[b][p][c] = sum_{i in tile, j in chunk} scores[b,i,j] * tanh(xd[b,i,c]*xt[b,j,c])
// Using tanh(x) = 1 - 2*r, r = 1/(1+exp2(x*2*log2e)):
//   sum s*(1-2r) = (sum s over tile)  -  2 * sum s*r
// grid = (8 i-tiles of 32, 4 j-chunks of 64, 16 = b*2 + c-half), 256 threads (c)
// ---------------------------------------------------------------------------
__device__ __forceinline__ float sig2r(float a) {
    // returns 1/(1 + exp2(a)); a already includes 2*log2(e)*x
    float e = __builtin_amdgcn_exp2f(a);
    return __builtin_amdgcn_rcpf(e + 1.0f);
}

__global__ __launch_bounds__(256)
void cp_partial_kernel(const float* __restrict__ xd, const float* __restrict__ xt,
                       const float* __restrict__ scores, float* __restrict__ partials)
{
    const int i0  = blockIdx.x << 5;            // 0..224
    const int j0  = blockIdx.y << 6;            // 0..192
    const int b   = blockIdx.z >> 1;
    const int tid = threadIdx.x;
    const int c   = ((blockIdx.z & 1) << 8) | tid;   // 0..511

    __shared__ float ws_[64][32];   // [jj][ii]
    __shared__ float red[256];

    // stage the scores tile (32 i x 64 j), also accumulate its sum
    const float* __restrict__ sb = scores + (size_t)b * L_ * L_;
    float wsum_l = 0.f;
    {
        const int jj = tid & 63;
        const int ib = (tid >> 6) << 3;   // 0,8,16,24
        #pragma unroll
        for (int r = 0; r < 8; ++r) {
            const float v = sb[(size_t)(i0 + ib + r) * L_ + j0 + jj];
            ws_[jj][ib + r] = v;
            wsum_l += v;
        }
    }
    red[tid] = wsum_l;
    __syncthreads();
    for (int s = 128; s > 0; s >>= 1) {
        if (tid < s) red[tid] += red[tid + s];
        __syncthreads();
    }
    const float wsum = red[0];

    // xd rows for this i-tile, pre-scaled by 2*log2(e)
    float xds[32];
    const float* __restrict__ xdb = xd + ((size_t)(b * L_ + i0)) * C_ + c;
    #pragma unroll
    for (int i = 0; i < 32; ++i)
        xds[i] = xdb[(size_t)i * C_] * 2.8853900817779268f;

    const float* __restrict__ xtb = xt + ((size_t)(b * L_ + j0)) * C_ + c;
    float a0 = 0.f, a1 = 0.f, a2 = 0.f, a3 = 0.f;
    for (int jj = 0; jj < 64; ++jj) {
        const float xtv = xtb[(size_t)jj * C_];
        #pragma unroll
        for (int i = 0; i < 32; i += 4) {
            const float4 w4 = *(const float4*)&ws_[jj][i];   // wave-uniform broadcast
            a0 = fmaf(w4.x, sig2r(xds[i + 0] * xtv), a0);
            a1 = fmaf(w4.y, sig2r(xds[i + 1] * xtv), a1);
            a2 = fmaf(w4.z, sig2r(xds[i + 2] * xtv), a2);
            a3 = fmaf(w4.w, sig2r(xds[i + 3] * xtv), a3);
        }
    }
    const float acc = (a0 + a1) + (a2 + a3);
    const float partial = wsum - 2.0f * acc;
    partials[(size_t)(b * 32 + (int)blockIdx.x * 4 + (int)blockIdx.y) * C_ + c] = partial;
}

// ---------------------------------------------------------------------------
// Kernel 4: cp[b,c] = (sum_p partial[b][p][c]) / sums[b];  out = cp @ Wf + bf
// grid = (8 o-chunks of 64, 8 batches), 512 threads.
// ---------------------------------------------------------------------------
__global__ __launch_bounds__(512)
void finalize_kernel(const float* __restrict__ partials, const float* __restrict__ sums,
                     const float* __restrict__ Wf, const float* __restrict__ bfv,
                     float* __restrict__ out)
{
    const int b = blockIdx.y;
    const int t = threadIdx.x;
    __shared__ float cp[C_];
    __shared__ float red[512];

    float s = 0.f;
    #pragma unroll
    for (int p = 0; p < 32; ++p)
        s += partials[(size_t)(b * 32 + p) * C_ + t];
    cp[t] = s;                       // un-normalized; normalize at the end (linear)
    __syncthreads();

    const float inv = 1.0f / sums[b];
    const int o  = ((int)blockIdx.x << 6) | (t & 63);
    const int c0 = (t >> 6) << 6;
    float acc = 0.f;
    #pragma unroll 8
    for (int i = 0; i < 64; ++i) {
        const int cc = c0 + i;
        acc = fmaf(cp[cc], Wf[(size_t)cc * OUT_ + o], acc);
    }
    red[t] = acc;
    __syncthreads();
    if (t < 64) {
        float a = 0.f;
        #pragma unroll
        for (int g = 0; g < 8; ++g) a += red[(g << 6) | t];
        out[(size_t)b * OUT_ + o] = fmaf(a, inv, bfv[o]);
    }
}

// ---------------------------------------------------------------------------
extern "C" void kernel_launch(void* const* d_in, const int* in_sizes, int n_in,
                              void* d_out, int out_size, void* d_ws, size_t ws_size,
                              hipStream_t stream)
{
    const float* xd = (const float*)d_in[0];
    const float* xt = (const float*)d_in[1];
    const float* Wc = (const float*)d_in[2];
    const float* bc = (const float*)d_in[3];
    const float* Wp = (const float*)d_in[4];
    const float* bp = (const float*)d_in[5];
    const float* Wf = (const float*)d_in[6];
    const float* bf = (const float*)d_in[7];
    float* out = (float*)d_out;

    // workspace layout (floats):
    float* ws       = (float*)d_ws;
    float* pt       = ws;                    // 8*256*512  = 1048576
    float* pc       = pt + 1048576;          // 1048576
    float* scores   = pc + 1048576;          // 8*256*256  = 524288
    float* sums     = scores + 524288;       // 64 (8 used)
    float* partials = sums + 64;             // 8*32*512   = 131072
    // total ~10.6 MB

    hipMemsetAsync(sums, 0, 8 * sizeof(float), stream);

    proj_kernel<<<dim3(8, 32, 2), 256, 0, stream>>>(xt, Wp, bp, xd, Wc, bc, pt, pc);
    scores_kernel<<<dim3(4, 4, 8), 256, 0, stream>>>(pt, pc, scores, sums);
    cp_partial_kernel<<<dim3(8, 4, 16), 256, 0, stream>>>(xd, xt, scores, partials);
    finalize_kernel<<<dim3(8, 8), 512, 0, stream>>>(partials, sums, Wf, bf, out);
}

// Round 3
// 194.147 us; speedup vs baseline: 1.1029x; 1.1029x over previous
//
#include <hip/hip_runtime.h>
#include <math.h>

// Problem constants
#define B_   8
#define L_   256
#define C_   512
#define OUT_ 512

// ---------------------------------------------------------------------------
// Kernel 1: fused relu-GEMM for both projections.
//   Y[m][n] = sum_k relu(X[m][k]) * W[k][n] + bias[n]
//   M = 2048, N = 512, K = 512. 64x64 tile, KT=32, double-buffered LDS,
//   register prefetch, 1 barrier/tile. grid (8,32,2), 256 thr, 4x4 micro.
// ---------------------------------------------------------------------------
__global__ __launch_bounds__(256, 4)
void proj_kernel(const float* __restrict__ xt, const float* __restrict__ Wp,
                 const float* __restrict__ bp,
                 const float* __restrict__ xd, const float* __restrict__ Wc,
                 const float* __restrict__ bc,
                 float* __restrict__ pt, float* __restrict__ pc)
{
    const int which = blockIdx.z;
    const float* __restrict__ X    = which ? xd : xt;
    const float* __restrict__ W    = which ? Wc : Wp;
    const float* __restrict__ bias = which ? bc : bp;
    float* __restrict__ Y          = which ? pc : pt;

    __shared__ float As[2][32][66];   // [buf][k][m] (pad 66 breaks write conflicts)
    __shared__ float Bs[2][32][64];   // [buf][k][n]

    const int tid = threadIdx.x;
    const int tx = tid & 15, ty = tid >> 4;
    const int m0 = blockIdx.y * 64, n0 = blockIdx.x * 64;

    const int am = tid >> 2;            // 0..63  A stage row
    const int ak = (tid & 3) << 3;      // 0,8,16,24
    const int bk = tid >> 3;            // 0..31  B stage k
    const int bn = (tid & 7) << 3;      // 0,8,...,56

    const float* Ap = X + (size_t)(m0 + am) * C_ + ak;
    const float* Bp = W + (size_t)bk * C_ + n0 + bn;

    float4 a0 = *(const float4*)(Ap + 0);
    float4 a1 = *(const float4*)(Ap + 4);
    float4 b0 = *(const float4*)(Bp + 0);
    float4 b1 = *(const float4*)(Bp + 4);

    float acc[4][4] = {};

    for (int t = 0; t < 16; ++t) {
        const int cur = t & 1;
        As[cur][ak + 0][am] = fmaxf(a0.x, 0.f);
        As[cur][ak + 1][am] = fmaxf(a0.y, 0.f);
        As[cur][ak + 2][am] = fmaxf(a0.z, 0.f);
        As[cur][ak + 3][am] = fmaxf(a0.w, 0.f);
        As[cur][ak + 4][am] = fmaxf(a1.x, 0.f);
        As[cur][ak + 5][am] = fmaxf(a1.y, 0.f);
        As[cur][ak + 6][am] = fmaxf(a1.z, 0.f);
        As[cur][ak + 7][am] = fmaxf(a1.w, 0.f);
        *(float4*)&Bs[cur][bk][bn]     = b0;
        *(float4*)&Bs[cur][bk][bn + 4] = b1;
        if (t < 15) {
            Ap += 32;             // A: K is the contiguous dim
            Bp += 32 * C_;        // B: K strides by rows (BUGFIX from round 2)
            a0 = *(const float4*)(Ap + 0);
            a1 = *(const float4*)(Ap + 4);
            b0 = *(const float4*)(Bp + 0);
            b1 = *(const float4*)(Bp + 4);
        }
        __syncthreads();
        #pragma unroll 8
        for (int kk = 0; kk < 32; ++kk) {
            float4 a = *(const float4*)&As[cur][kk][ty << 2];
            float4 b = *(const float4*)&Bs[cur][kk][tx << 2];
            float ar[4] = {a.x, a.y, a.z, a.w};
            float br[4] = {b.x, b.y, b.z, b.w};
            #pragma unroll
            for (int i = 0; i < 4; ++i)
                #pragma unroll
                for (int j = 0; j < 4; ++j)
                    acc[i][j] = fmaf(ar[i], br[j], acc[i][j]);
        }
        __syncthreads();
    }

    const float4 bv = *(const float4*)&bias[n0 + (tx << 2)];
    #pragma unroll
    for (int i = 0; i < 4; ++i) {
        const int m = m0 + (ty << 2) + i;
        float4 o;
        o.x = acc[i][0] + bv.x; o.y = acc[i][1] + bv.y;
        o.z = acc[i][2] + bv.z; o.w = acc[i][3] + bv.w;
        *(float4*)&Y[(size_t)m * C_ + n0 + (tx << 2)] = o;
    }
}

// ---------------------------------------------------------------------------
// Kernel 2a: dot[ks][b][i][j] = sum_{c in K-half ks} pt[b,i,c] * pc[b,j,c]
// K-split x2 for occupancy: grid (4,4,16=b*2+ks), 64x64 tile, KT=32, dbuf.
// ---------------------------------------------------------------------------
__global__ __launch_bounds__(256, 4)
void sc_gemm_kernel(const float* __restrict__ pt, const float* __restrict__ pc,
                    float* __restrict__ dot0, float* __restrict__ dot1)
{
    const int b  = blockIdx.z >> 1;
    const int ks = blockIdx.z & 1;
    const float* __restrict__ A  = pt + (size_t)b * L_ * C_ + (ks << 8);
    const float* __restrict__ Bm = pc + (size_t)b * L_ * C_ + (ks << 8);
    float* __restrict__ D = (ks ? dot1 : dot0) + (size_t)b * L_ * L_;

    __shared__ float As[2][32][66];   // [buf][k][i]
    __shared__ float Bs[2][32][66];   // [buf][k][j]

    const int tid = threadIdx.x;
    const int tx = tid & 15, ty = tid >> 4;
    const int m0 = blockIdx.y * 64, n0 = blockIdx.x * 64;

    const int am = tid >> 2;        // 0..63
    const int ak = (tid & 3) << 3;  // 0,8,16,24

    const float* Ap = A  + (size_t)(m0 + am) * C_ + ak;
    const float* Bp = Bm + (size_t)(n0 + am) * C_ + ak;

    float4 a0 = *(const float4*)(Ap + 0);
    float4 a1 = *(const float4*)(Ap + 4);
    float4 b0 = *(const float4*)(Bp + 0);
    float4 b1 = *(const float4*)(Bp + 4);

    float acc[4][4] = {};

    for (int t = 0; t < 8; ++t) {
        const int cur = t & 1;
        As[cur][ak + 0][am] = a0.x;  As[cur][ak + 1][am] = a0.y;
        As[cur][ak + 2][am] = a0.z;  As[cur][ak + 3][am] = a0.w;
        As[cur][ak + 4][am] = a1.x;  As[cur][ak + 5][am] = a1.y;
        As[cur][ak + 6][am] = a1.z;  As[cur][ak + 7][am] = a1.w;
        Bs[cur][ak + 0][am] = b0.x;  Bs[cur][ak + 1][am] = b0.y;
        Bs[cur][ak + 2][am] = b0.z;  Bs[cur][ak + 3][am] = b0.w;
        Bs[cur][ak + 4][am] = b1.x;  Bs[cur][ak + 5][am] = b1.y;
        Bs[cur][ak + 6][am] = b1.z;  Bs[cur][ak + 7][am] = b1.w;
        if (t < 7) {
            Ap += 32; Bp += 32;   // both operands are K-contiguous here
            a0 = *(const float4*)(Ap + 0);
            a1 = *(const float4*)(Ap + 4);
            b0 = *(const float4*)(Bp + 0);
            b1 = *(const float4*)(Bp + 4);
        }
        __syncthreads();
        #pragma unroll 8
        for (int kk = 0; kk < 32; ++kk) {
            float4 a = *(const float4*)&As[cur][kk][ty << 2];
            float4 b = *(const float4*)&Bs[cur][kk][tx << 2];
            float ar[4] = {a.x, a.y, a.z, a.w};
            float br[4] = {b.x, b.y, b.z, b.w};
            #pragma unroll
            for (int i = 0; i < 4; ++i)
                #pragma unroll
                for (int j = 0; j < 4; ++j)
                    acc[i][j] = fmaf(ar[i], br[j], acc[i][j]);
        }
        __syncthreads();
    }

    #pragma unroll
    for (int i = 0; i < 4; ++i) {
        const int m = m0 + (ty << 2) + i;
        float4 o = {acc[i][0], acc[i][1], acc[i][2], acc[i][3]};
        *(float4*)&D[(size_t)m * L_ + n0 + (tx << 2)] = o;
    }
}

// ---------------------------------------------------------------------------
// Kernel 2b: scores = sigmoid(dot0+dot1) (in-place into dot0) + per-batch sums
// grid 512 blocks x 256 thr, 4 elems/thread.
// ---------------------------------------------------------------------------
__global__ __launch_bounds__(256)
void sc_finish_kernel(float* __restrict__ dot0, const float* __restrict__ dot1,
                      float* __restrict__ sums)
{
    __shared__ float red[256];
    const int bl = blockIdx.x;
    const int b  = bl >> 6;
    const size_t base = (size_t)b * (L_ * L_) + (size_t)((bl & 63) << 10) + ((size_t)threadIdx.x << 2);
    float4 d0 = *(const float4*)&dot0[base];
    float4 d1 = *(const float4*)&dot1[base];
    float4 s;
    s.x = 1.0f / (1.0f + expf(-(d0.x + d1.x)));
    s.y = 1.0f / (1.0f + expf(-(d0.y + d1.y)));
    s.z = 1.0f / (1.0f + expf(-(d0.z + d1.z)));
    s.w = 1.0f / (1.0f + expf(-(d0.w + d1.w)));
    *(float4*)&dot0[base] = s;
    red[threadIdx.x] = (s.x + s.y) + (s.z + s.w);
    __syncthreads();
    for (int st = 128; st > 0; st >>= 1) {
        if (threadIdx.x < st) red[threadIdx.x] += red[threadIdx.x + st];
        __syncthreads();
    }
    if (threadIdx.x == 0) atomicAdd(&sums[b], red[0]);
}

// ---------------------------------------------------------------------------
// Kernel 3: partial[b][p][c] = sum_{i,j in 32x32 tile} w[i,j]*tanh(xd[i,c]*xt[j,c])
// tanh(x) = 1 - 2r, r = 1/(1+exp2(2*log2e*x)):  sum w*(1-2r) = wsum - 2*sum(w*r)
// grid (8 i-tiles, 8 j-tiles, 16=b*2+c-half), 256 thr (c). xt/xd rows in regs.
// ---------------------------------------------------------------------------
__device__ __forceinline__ float sig2r(float a) {
    float e = __builtin_amdgcn_exp2f(a);
    return __builtin_amdgcn_rcpf(e + 1.0f);
}

__global__ __launch_bounds__(256, 4)
void cp_partial_kernel(const float* __restrict__ xd, const float* __restrict__ xt,
                       const float* __restrict__ scores, float* __restrict__ partials)
{
    const int i0  = blockIdx.x << 5;
    const int j0  = blockIdx.y << 5;
    const int b   = blockIdx.z >> 1;
    const int tid = threadIdx.x;
    const int c   = ((blockIdx.z & 1) << 8) | tid;

    __shared__ float ws_[32][36];   // [jj][ii], pad 36: conflict-free stage, 16B-aligned rows
    __shared__ float red[256];

    const float* __restrict__ sb = scores + (size_t)b * L_ * L_;
    float wsum_l = 0.f;
    {
        const int jj = tid & 31;
        const int ib = (tid >> 5) << 2;   // 0,4,...,28
        #pragma unroll
        for (int r = 0; r < 4; ++r) {
            const float v = sb[(size_t)(i0 + ib + r) * L_ + j0 + jj];
            ws_[jj][ib + r] = v;
            wsum_l += v;
        }
    }
    red[tid] = wsum_l;
    __syncthreads();
    for (int s = 128; s > 0; s >>= 1) {
        if (tid < s) red[tid] += red[tid + s];
        __syncthreads();
    }
    const float wsum = red[0];

    float xds[32], xtv[32];
    const float* __restrict__ xdb = xd + ((size_t)(b * L_ + i0)) * C_ + c;
    const float* __restrict__ xtb = xt + ((size_t)(b * L_ + j0)) * C_ + c;
    #pragma unroll
    for (int i = 0; i < 32; ++i)
        xds[i] = xdb[(size_t)i * C_] * 2.8853900817779268f;   // 2*log2(e)
    #pragma unroll
    for (int j = 0; j < 32; ++j)
        xtv[j] = xtb[(size_t)j * C_];

    float a0 = 0.f, a1 = 0.f, a2 = 0.f, a3 = 0.f;
    #pragma unroll 4
    for (int jj = 0; jj < 32; ++jj) {
        const float xv = xtv[jj];
        #pragma unroll
        for (int i = 0; i < 32; i += 4) {
            const float4 w4 = *(const float4*)&ws_[jj][i];   // wave-uniform broadcast
            a0 = fmaf(w4.x, sig2r(xds[i + 0] * xv), a0);
            a1 = fmaf(w4.y, sig2r(xds[i + 1] * xv), a1);
            a2 = fmaf(w4.z, sig2r(xds[i + 2] * xv), a2);
            a3 = fmaf(w4.w, sig2r(xds[i + 3] * xv), a3);
        }
    }
    const float acc = (a0 + a1) + (a2 + a3);
    const float partial = wsum - 2.0f * acc;
    const int p = ((int)blockIdx.x << 3) | (int)blockIdx.y;
    partials[(size_t)((b << 6) | p) * C_ + c] = partial;
}

// ---------------------------------------------------------------------------
// Kernel 4: cp[b,c] = (sum_p partial[b][p][c]) / sums[b];  out = cp @ Wf + bf
// ---------------------------------------------------------------------------
__global__ __launch_bounds__(512)
void finalize_kernel(const float* __restrict__ partials, const float* __restrict__ sums,
                     const float* __restrict__ Wf, const float* __restrict__ bfv,
                     float* __restrict__ out)
{
    const int b = blockIdx.y;
    const int t = threadIdx.x;
    __shared__ float cp[C_];
    __shared__ float red[512];

    float s = 0.f;
    #pragma unroll
    for (int p = 0; p < 64; ++p)
        s += partials[(size_t)((b << 6) | p) * C_ + t];
    cp[t] = s;                       // normalize at the end (linear)
    __syncthreads();

    const float inv = 1.0f / sums[b];
    const int o  = ((int)blockIdx.x << 6) | (t & 63);
    const int c0 = (t >> 6) << 6;
    float acc = 0.f;
    #pragma unroll 8
    for (int i = 0; i < 64; ++i) {
        const int cc = c0 + i;
        acc = fmaf(cp[cc], Wf[(size_t)cc * OUT_ + o], acc);
    }
    red[t] = acc;
    __syncthreads();
    if (t < 64) {
        float a = 0.f;
        #pragma unroll
        for (int g = 0; g < 8; ++g) a += red[(g << 6) | t];
        out[(size_t)b * OUT_ + o] = fmaf(a, inv, bfv[o]);
    }
}

// ---------------------------------------------------------------------------
extern "C" void kernel_launch(void* const* d_in, const int* in_sizes, int n_in,
                              void* d_out, int out_size, void* d_ws, size_t ws_size,
                              hipStream_t stream)
{
    const float* xd = (const float*)d_in[0];
    const float* xt = (const float*)d_in[1];
    const float* Wc = (const float*)d_in[2];
    const float* bc = (const float*)d_in[3];
    const float* Wp = (const float*)d_in[4];
    const float* bp = (const float*)d_in[5];
    const float* Wf = (const float*)d_in[6];
    const float* bf = (const float*)d_in[7];
    float* out = (float*)d_out;

    // workspace layout (floats): ~13.6 MB
    float* ws       = (float*)d_ws;
    float* pt       = ws;                    // 1048576
    float* pc       = pt + 1048576;          // 1048576
    float* dot0     = pc + 1048576;          // 524288 (becomes scores in-place)
    float* dot1     = dot0 + 524288;         // 524288
    float* sums     = dot1 + 524288;         // 64 (8 used)
    float* partials = sums + 64;             // 8*64*512 = 262144

    hipMemsetAsync(sums, 0, 8 * sizeof(float), stream);

    proj_kernel<<<dim3(8, 32, 2), 256, 0, stream>>>(xt, Wp, bp, xd, Wc, bc, pt, pc);
    sc_gemm_kernel<<<dim3(4, 4, 16), 256, 0, stream>>>(pt, pc, dot0, dot1);
    sc_finish_kernel<<<512, 256, 0, stream>>>(dot0, dot1, sums);
    cp_partial_kernel<<<dim3(8, 8, 16), 256, 0, stream>>>(xd, xt, dot0, partials);
    finalize_kernel<<<dim3(8, 8), 512, 0, stream>>>(partials, sums, Wf, bf, out);
}

// Round 4
// 156.288 us; speedup vs baseline: 1.3701x; 1.2422x over previous
//
#include <hip/hip_runtime.h>
#include <math.h>

// Problem constants
#define B_   8
#define L_   256
#define C_   512
#define OUT_ 512

typedef _Float16 half8 __attribute__((ext_vector_type(8)));
typedef float    f32x4 __attribute__((ext_vector_type(4)));

// ---------------------------------------------------------------------------
// Kernel 0: weight convert+transpose: hW[n][k] = (f16) W[k][n], for Wp and Wc.
// grid (16,16,2), 256 thr, 32x32 LDS tile transpose.
// ---------------------------------------------------------------------------
__global__ __launch_bounds__(256)
void wconv_kernel(const float* __restrict__ Wp, const float* __restrict__ Wc,
                  _Float16* __restrict__ hWp, _Float16* __restrict__ hWc)
{
    const int which = blockIdx.z;
    const float* __restrict__ W = which ? Wc : Wp;
    _Float16* __restrict__ H    = which ? hWc : hWp;
    __shared__ float tl[32][33];
    const int k0 = blockIdx.y << 5, n0 = blockIdx.x << 5;
    const int tr = threadIdx.x >> 5, tc = threadIdx.x & 31;
    #pragma unroll
    for (int i = 0; i < 32; i += 8)
        tl[tr + i][tc] = W[(size_t)(k0 + tr + i) * C_ + n0 + tc];
    __syncthreads();
    #pragma unroll
    for (int i = 0; i < 32; i += 8)
        H[(size_t)(n0 + tr + i) * C_ + k0 + tc] = (_Float16)tl[tc][tr + i];
}

// ---------------------------------------------------------------------------
// Kernel 1: MFMA relu-GEMM projections (f16 in, f32 acc, f16 out).
//   Y[m][n] = sum_k relu(X[m][k]) * W[k][n] + bias[n],  hW stored [n][k].
// 64x64 tile, K-step 32, 4 waves x 4 MFMA(16x16x32) per step. grid (8,32,2).
// A layout: m=lane&15, k=quad*8+i ; B: n=lane&15, k=quad*8+i (B^T form, m92).
// C/D: col=lane&15, row=quad*4+reg (m89/m91 verified).
// ---------------------------------------------------------------------------
__global__ __launch_bounds__(256)
void proj_mfma_kernel(const float* __restrict__ xt, const _Float16* __restrict__ hWp,
                      const float* __restrict__ bp,
                      const float* __restrict__ xd, const _Float16* __restrict__ hWc,
                      const float* __restrict__ bc,
                      _Float16* __restrict__ pt, _Float16* __restrict__ pc)
{
    const int which = blockIdx.z;
    const float*    __restrict__ X    = which ? xd : xt;
    const _Float16* __restrict__ W    = which ? hWc : hWp;
    const float*    __restrict__ bias = which ? bc : bp;
    _Float16*       __restrict__ Y    = which ? pc : pt;

    __shared__ _Float16 Ah[64][40];   // pad 40 halves: 2-way bank alias only (free)
    __shared__ _Float16 Bh[64][40];
    __shared__ _Float16 Ot[64][72];   // epilogue staging for coalesced f16 stores

    const int tid = threadIdx.x;
    const int m0 = blockIdx.y << 6, n0 = blockIdx.x << 6;
    const int srow = tid >> 2, sch = (tid & 3) << 3;   // staging: row, 8-elem chunk
    const int lane = tid & 63, wv = tid >> 6;
    const int l15 = lane & 15, quad = lane >> 4;

    f32x4 acc[4] = {};
    const float*    Ag = X + (size_t)(m0 + srow) * C_ + sch;
    const _Float16* Bg = W + (size_t)(n0 + srow) * C_ + sch;

    for (int ks = 0; ks < 16; ++ks) {
        float4 a0 = *(const float4*)(Ag);
        float4 a1 = *(const float4*)(Ag + 4);
        half8 bv = *(const half8*)(Bg);
        Ag += 32; Bg += 32;
        half8 av;
        av[0] = (_Float16)fmaxf(a0.x, 0.f);
        av[1] = (_Float16)fmaxf(a0.y, 0.f);
        av[2] = (_Float16)fmaxf(a0.z, 0.f);
        av[3] = (_Float16)fmaxf(a0.w, 0.f);
        av[4] = (_Float16)fmaxf(a1.x, 0.f);
        av[5] = (_Float16)fmaxf(a1.y, 0.f);
        av[6] = (_Float16)fmaxf(a1.z, 0.f);
        av[7] = (_Float16)fmaxf(a1.w, 0.f);
        *(half8*)&Ah[srow][sch] = av;
        *(half8*)&Bh[srow][sch] = bv;
        __syncthreads();
        half8 af = *(const half8*)&Ah[(wv << 4) + l15][quad << 3];
        #pragma unroll
        for (int nb = 0; nb < 4; ++nb) {
            half8 bf = *(const half8*)&Bh[(nb << 4) + l15][quad << 3];
            acc[nb] = __builtin_amdgcn_mfma_f32_16x16x32_f16(af, bf, acc[nb], 0, 0, 0);
        }
        __syncthreads();
    }

    #pragma unroll
    for (int nb = 0; nb < 4; ++nb) {
        const float bz = bias[n0 + (nb << 4) + l15];
        #pragma unroll
        for (int r = 0; r < 4; ++r)
            Ot[(wv << 4) + (quad << 2) + r][(nb << 4) + l15] = (_Float16)(acc[nb][r] + bz);
    }
    __syncthreads();
    const int erow = tid >> 3, ech = (tid & 7) << 3;
    #pragma unroll
    for (int h = 0; h < 64; h += 32)
        *(half8*)&Y[(size_t)(m0 + erow + h) * C_ + n0 + ech] = *(const half8*)&Ot[erow + h][ech];
}

// ---------------------------------------------------------------------------
// Kernel 2a: MFMA score GEMM: dot[ks][b][i][j] = sum_{c in half ks} pt.pc
// Both operands f16 [row][c] (K-contiguous). grid (4,4,16=b*2+ks), 64x64 tile.
// ---------------------------------------------------------------------------
__global__ __launch_bounds__(256)
void sc_gemm_mfma_kernel(const _Float16* __restrict__ pt, const _Float16* __restrict__ pc,
                         float* __restrict__ dot0, float* __restrict__ dot1)
{
    const int b = blockIdx.z >> 1, ks = blockIdx.z & 1;
    const _Float16* __restrict__ A  = pt + (size_t)b * L_ * C_ + (ks << 8);
    const _Float16* __restrict__ Bm = pc + (size_t)b * L_ * C_ + (ks << 8);
    float* __restrict__ D = (ks ? dot1 : dot0) + (size_t)b * L_ * L_;

    __shared__ _Float16 Ah[64][40];
    __shared__ _Float16 Bh[64][40];

    const int tid = threadIdx.x;
    const int m0 = blockIdx.y << 6, n0 = blockIdx.x << 6;
    const int srow = tid >> 2, sch = (tid & 3) << 3;
    const int lane = tid & 63, wv = tid >> 6;
    const int l15 = lane & 15, quad = lane >> 4;

    f32x4 acc[4] = {};
    const _Float16* Ag = A  + (size_t)(m0 + srow) * C_ + sch;
    const _Float16* Bg = Bm + (size_t)(n0 + srow) * C_ + sch;

    for (int t = 0; t < 8; ++t) {
        half8 av = *(const half8*)Ag;
        half8 bv = *(const half8*)Bg;
        Ag += 32; Bg += 32;
        *(half8*)&Ah[srow][sch] = av;
        *(half8*)&Bh[srow][sch] = bv;
        __syncthreads();
        half8 af = *(const half8*)&Ah[(wv << 4) + l15][quad << 3];
        #pragma unroll
        for (int nb = 0; nb < 4; ++nb) {
            half8 bf = *(const half8*)&Bh[(nb << 4) + l15][quad << 3];
            acc[nb] = __builtin_amdgcn_mfma_f32_16x16x32_f16(af, bf, acc[nb], 0, 0, 0);
        }
        __syncthreads();
    }
    #pragma unroll
    for (int nb = 0; nb < 4; ++nb)
        #pragma unroll
        for (int r = 0; r < 4; ++r)
            D[(size_t)(m0 + (wv << 4) + (quad << 2) + r) * L_ + n0 + (nb << 4) + l15] = acc[nb][r];
}

// ---------------------------------------------------------------------------
// Kernel 2b: scores = sigmoid(dot0+dot1) in-place into dot0 + per-block sums.
// grid 512 x 256 thr; sums_part[bl], batch = bl>>6 (no atomics, no memset).
// ---------------------------------------------------------------------------
__global__ __launch_bounds__(256)
void sc_finish_kernel(float* __restrict__ dot0, const float* __restrict__ dot1,
                      float* __restrict__ sums_part)
{
    __shared__ float red[256];
    const int bl = blockIdx.x;
    const int b  = bl >> 6;
    const size_t base = (size_t)b * (L_ * L_) + (size_t)((bl & 63) << 10) + ((size_t)threadIdx.x << 2);
    float4 d0 = *(const float4*)&dot0[base];
    float4 d1 = *(const float4*)&dot1[base];
    float4 s;
    s.x = 1.0f / (1.0f + expf(-(d0.x + d1.x)));
    s.y = 1.0f / (1.0f + expf(-(d0.y + d1.y)));
    s.z = 1.0f / (1.0f + expf(-(d0.z + d1.z)));
    s.w = 1.0f / (1.0f + expf(-(d0.w + d1.w)));
    *(float4*)&dot0[base] = s;
    red[threadIdx.x] = (s.x + s.y) + (s.z + s.w);
    __syncthreads();
    for (int st = 128; st > 0; st >>= 1) {
        if (threadIdx.x < st) red[threadIdx.x] += red[threadIdx.x + st];
        __syncthreads();
    }
    if (threadIdx.x == 0) sums_part[bl] = red[0];
}

// ---------------------------------------------------------------------------
// Kernel 3: partial[b][p][c] = sum_{32i x 16j tile} w[i,j]*tanh(xd[i,c]*xt[j,c])
// tanh(x) = 1-2r, r = 1/(1+exp2(2*log2e*x)): sum w*(1-2r) = wsum - 2*sum(w*r)
// grid (8,16,16=b*2+chalf) = 2048 blocks (8 blocks/CU -> full wave cap).
// ---------------------------------------------------------------------------
__device__ __forceinline__ float sig2r(float a) {
    float e = __builtin_amdgcn_exp2f(a);
    return __builtin_amdgcn_rcpf(e + 1.0f);
}

__global__ __launch_bounds__(256, 4)
void cp_partial_kernel(const float* __restrict__ xd, const float* __restrict__ xt,
                       const float* __restrict__ scores, float* __restrict__ partials)
{
    const int i0  = blockIdx.x << 5;
    const int j0  = blockIdx.y << 4;
    const int b   = blockIdx.z >> 1;
    const int tid = threadIdx.x;
    const int c   = ((blockIdx.z & 1) << 8) | tid;

    __shared__ float ws_[16][36];
    __shared__ float red[256];

    const float* __restrict__ sb = scores + (size_t)b * L_ * L_;
    float wl = 0.f;
    {
        const int jj = tid & 15;
        const int ib = (tid >> 4) << 1;   // 0..30 step 2
        #pragma unroll
        for (int r = 0; r < 2; ++r) {
            const float v = sb[(size_t)(i0 + ib + r) * L_ + j0 + jj];
            ws_[jj][ib + r] = v;
            wl += v;
        }
    }
    red[tid] = wl;
    __syncthreads();
    for (int s = 128; s > 0; s >>= 1) {
        if (tid < s) red[tid] += red[tid + s];
        __syncthreads();
    }
    const float wsum = red[0];

    float xds[32], xtv[16];
    const float* __restrict__ xdb = xd + ((size_t)(b * L_ + i0)) * C_ + c;
    const float* __restrict__ xtb = xt + ((size_t)(b * L_ + j0)) * C_ + c;
    #pragma unroll
    for (int i = 0; i < 32; ++i)
        xds[i] = xdb[(size_t)i * C_] * 2.8853900817779268f;   // 2*log2(e)
    #pragma unroll
    for (int j = 0; j < 16; ++j)
        xtv[j] = xtb[(size_t)j * C_];

    float a0 = 0.f, a1 = 0.f, a2 = 0.f, a3 = 0.f;
    #pragma unroll 2
    for (int jj = 0; jj < 16; ++jj) {
        const float xv = xtv[jj];
        #pragma unroll
        for (int i = 0; i < 32; i += 4) {
            const float4 w4 = *(const float4*)&ws_[jj][i];   // wave-uniform broadcast
            a0 = fmaf(w4.x, sig2r(xds[i + 0] * xv), a0);
            a1 = fmaf(w4.y, sig2r(xds[i + 1] * xv), a1);
            a2 = fmaf(w4.z, sig2r(xds[i + 2] * xv), a2);
            a3 = fmaf(w4.w, sig2r(xds[i + 3] * xv), a3);
        }
    }
    const float partial = wsum - 2.0f * ((a0 + a1) + (a2 + a3));
    const int p = ((int)blockIdx.x << 4) | (int)blockIdx.y;   // 0..127
    partials[(size_t)((b << 7) | p) * C_ + c] = partial;
}

// ---------------------------------------------------------------------------
// Kernel 4: cp[b,c] = sum_p partial / sum(scores);  out = cp @ Wf + bf
// Also reduces the 64 per-block score sums for its batch. grid (8,8), 512 thr.
// ---------------------------------------------------------------------------
__global__ __launch_bounds__(512)
void finalize_kernel(const float* __restrict__ partials, const float* __restrict__ sums_part,
                     const float* __restrict__ Wf, const float* __restrict__ bfv,
                     float* __restrict__ out)
{
    const int b = blockIdx.y;
    const int t = threadIdx.x;
    __shared__ float cp[C_];
    __shared__ float red[512];
    __shared__ float sumsh;

    float s = 0.f;
    #pragma unroll
    for (int p = 0; p < 128; ++p)
        s += partials[(size_t)((b << 7) | p) * C_ + t];
    cp[t] = s;                          // normalize at the end (linear)

    red[t] = (t < 64) ? sums_part[(b << 6) | t] : 0.f;
    __syncthreads();
    for (int st = 256; st > 0; st >>= 1) {
        if (t < st) red[t] += red[t + st];
        __syncthreads();
    }
    if (t == 0) sumsh = red[0];
    __syncthreads();

    const float inv = 1.0f / sumsh;
    const int o  = ((int)blockIdx.x << 6) | (t & 63);
    const int c0 = (t >> 6) << 6;
    float acc = 0.f;
    #pragma unroll 8
    for (int i = 0; i < 64; ++i) {
        const int cc = c0 + i;
        acc = fmaf(cp[cc], Wf[(size_t)cc * OUT_ + o], acc);
    }
    red[t] = acc;
    __syncthreads();
    if (t < 64) {
        float a = 0.f;
        #pragma unroll
        for (int g = 0; g < 8; ++g) a += red[(g << 6) | t];
        out[(size_t)b * OUT_ + o] = fmaf(a, inv, bfv[o]);
    }
}

// ---------------------------------------------------------------------------
extern "C" void kernel_launch(void* const* d_in, const int* in_sizes, int n_in,
                              void* d_out, int out_size, void* d_ws, size_t ws_size,
                              hipStream_t stream)
{
    const float* xd = (const float*)d_in[0];
    const float* xt = (const float*)d_in[1];
    const float* Wc = (const float*)d_in[2];
    const float* bc = (const float*)d_in[3];
    const float* Wp = (const float*)d_in[4];
    const float* bp = (const float*)d_in[5];
    const float* Wf = (const float*)d_in[6];
    const float* bf = (const float*)d_in[7];
    float* out = (float*)d_out;

    // workspace layout: ~11 MB, every consumed byte is written by a kernel first
    _Float16* hWp = (_Float16*)d_ws;                 // 256K halves (512 KB)
    _Float16* hWc = hWp + 262144;                    // 512 KB
    _Float16* pt  = hWc + 262144;                    // 1M halves (2 MB)
    _Float16* pc  = pt + 1048576;                    // 2 MB
    float* dot0      = (float*)(pc + 1048576);       // 512K fl (2 MB), -> scores
    float* dot1      = dot0 + 524288;                // 2 MB
    float* sums_part = dot1 + 524288;                // 512 fl
    float* partials  = sums_part + 512;              // 512K fl (2 MB)

    wconv_kernel<<<dim3(16, 16, 2), 256, 0, stream>>>(Wp, Wc, hWp, hWc);
    proj_mfma_kernel<<<dim3(8, 32, 2), 256, 0, stream>>>(xt, hWp, bp, xd, hWc, bc, pt, pc);
    sc_gemm_mfma_kernel<<<dim3(4, 4, 16), 256, 0, stream>>>(pt, pc, dot0, dot1);
    sc_finish_kernel<<<512, 256, 0, stream>>>(dot0, dot1, sums_part);
    cp_partial_kernel<<<dim3(8, 16, 16), 256, 0, stream>>>(xd, xt, dot0, partials);
    finalize_kernel<<<dim3(8, 8), 512, 0, stream>>>(partials, sums_part, Wf, bf, out);
}

// Round 5
// 153.854 us; speedup vs baseline: 1.3918x; 1.0158x over previous
//
#include <hip/hip_runtime.h>
#include <math.h>

// Problem constants
#define B_   8
#define L_   256
#define C_   512
#define OUT_ 512

typedef _Float16 half8 __attribute__((ext_vector_type(8)));
typedef float    f32x4 __attribute__((ext_vector_type(4)));

// ---------------------------------------------------------------------------
// Kernel 0: weight convert+transpose: hW[n][k] = (f16) W[k][n], for Wp and Wc.
// ---------------------------------------------------------------------------
__global__ __launch_bounds__(256)
void wconv_kernel(const float* __restrict__ Wp, const float* __restrict__ Wc,
                  _Float16* __restrict__ hWp, _Float16* __restrict__ hWc)
{
    const int which = blockIdx.z;
    const float* __restrict__ W = which ? Wc : Wp;
    _Float16* __restrict__ H    = which ? hWc : hWp;
    __shared__ float tl[32][33];
    const int k0 = blockIdx.y << 5, n0 = blockIdx.x << 5;
    const int tr = threadIdx.x >> 5, tc = threadIdx.x & 31;
    #pragma unroll
    for (int i = 0; i < 32; i += 8)
        tl[tr + i][tc] = W[(size_t)(k0 + tr + i) * C_ + n0 + tc];
    __syncthreads();
    #pragma unroll
    for (int i = 0; i < 32; i += 8)
        H[(size_t)(n0 + tr + i) * C_ + k0 + tc] = (_Float16)tl[tc][tr + i];
}

// ---------------------------------------------------------------------------
// Kernel 1: MFMA relu-GEMM projections (f16 in, f32 acc, f16 out).
// 64x64 tile, K-step 32, double-buffered LDS, 1 barrier/step. grid (8,32,2).
// A frag: m=lane&15, k=quad*8+i ; B frag: n=lane&15, k=quad*8+i (B^T form).
// C/D: col=lane&15, row=quad*4+reg.
// ---------------------------------------------------------------------------
__global__ __launch_bounds__(256)
void proj_mfma_kernel(const float* __restrict__ xt, const _Float16* __restrict__ hWp,
                      const float* __restrict__ bp,
                      const float* __restrict__ xd, const _Float16* __restrict__ hWc,
                      const float* __restrict__ bc,
                      _Float16* __restrict__ pt, _Float16* __restrict__ pc)
{
    const int which = blockIdx.z;
    const float*    __restrict__ X    = which ? xd : xt;
    const _Float16* __restrict__ W    = which ? hWc : hWp;
    const float*    __restrict__ bias = which ? bc : bp;
    _Float16*       __restrict__ Y    = which ? pc : pt;

    __shared__ _Float16 Ah[2][64][40];   // pad 40: 2-way bank alias only (free)
    __shared__ _Float16 Bh[2][64][40];
    __shared__ _Float16 Ot[64][72];      // epilogue staging

    const int tid = threadIdx.x;
    const int m0 = blockIdx.y << 6, n0 = blockIdx.x << 6;
    const int srow = tid >> 2, sch = (tid & 3) << 3;
    const int lane = tid & 63, wv = tid >> 6;
    const int l15 = lane & 15, quad = lane >> 4;

    const float*    Ag = X + (size_t)(m0 + srow) * C_ + sch;
    const _Float16* Bg = W + (size_t)(n0 + srow) * C_ + sch;

    float4 a0 = *(const float4*)(Ag);
    float4 a1 = *(const float4*)(Ag + 4);
    half8  bv = *(const half8*)(Bg);

    // write buffer 0
    {
        half8 av;
        av[0] = (_Float16)fmaxf(a0.x, 0.f); av[1] = (_Float16)fmaxf(a0.y, 0.f);
        av[2] = (_Float16)fmaxf(a0.z, 0.f); av[3] = (_Float16)fmaxf(a0.w, 0.f);
        av[4] = (_Float16)fmaxf(a1.x, 0.f); av[5] = (_Float16)fmaxf(a1.y, 0.f);
        av[6] = (_Float16)fmaxf(a1.z, 0.f); av[7] = (_Float16)fmaxf(a1.w, 0.f);
        *(half8*)&Ah[0][srow][sch] = av;
        *(half8*)&Bh[0][srow][sch] = bv;
    }

    f32x4 acc[4] = {};
    for (int ks = 0; ks < 16; ++ks) {
        const int cur = ks & 1;
        if (ks < 15) {                        // prefetch next tile into regs
            Ag += 32; Bg += 32;
            a0 = *(const float4*)(Ag);
            a1 = *(const float4*)(Ag + 4);
            bv = *(const half8*)(Bg);
        }
        __syncthreads();                      // buf `cur` ready for all waves
        half8 af = *(const half8*)&Ah[cur][(wv << 4) + l15][quad << 3];
        #pragma unroll
        for (int nb = 0; nb < 4; ++nb) {
            half8 bf = *(const half8*)&Bh[cur][(nb << 4) + l15][quad << 3];
            acc[nb] = __builtin_amdgcn_mfma_f32_16x16x32_f16(af, bf, acc[nb], 0, 0, 0);
        }
        if (ks < 15) {                        // stage next into other buffer
            half8 av;
            av[0] = (_Float16)fmaxf(a0.x, 0.f); av[1] = (_Float16)fmaxf(a0.y, 0.f);
            av[2] = (_Float16)fmaxf(a0.z, 0.f); av[3] = (_Float16)fmaxf(a0.w, 0.f);
            av[4] = (_Float16)fmaxf(a1.x, 0.f); av[5] = (_Float16)fmaxf(a1.y, 0.f);
            av[6] = (_Float16)fmaxf(a1.z, 0.f); av[7] = (_Float16)fmaxf(a1.w, 0.f);
            *(half8*)&Ah[cur ^ 1][srow][sch] = av;
            *(half8*)&Bh[cur ^ 1][srow][sch] = bv;
        }
    }

    __syncthreads();
    #pragma unroll
    for (int nb = 0; nb < 4; ++nb) {
        const float bz = bias[n0 + (nb << 4) + l15];
        #pragma unroll
        for (int r = 0; r < 4; ++r)
            Ot[(wv << 4) + (quad << 2) + r][(nb << 4) + l15] = (_Float16)(acc[nb][r] + bz);
    }
    __syncthreads();
    const int erow = tid >> 3, ech = (tid & 7) << 3;
    #pragma unroll
    for (int h = 0; h < 64; h += 32)
        *(half8*)&Y[(size_t)(m0 + erow + h) * C_ + n0 + ech] = *(const half8*)&Ot[erow + h][ech];
}

// ---------------------------------------------------------------------------
// Kernel 2a: MFMA score GEMM, K-split x4 for occupancy (512 blocks).
//   dot[ks][b][i][j] = sum_{c in quarter ks} pt.pc ; grid (4,4,32=b*4+ks).
// Double-buffered, 1 barrier/step, 4 steps of KT=32.
// ---------------------------------------------------------------------------
__global__ __launch_bounds__(256)
void sc_gemm_mfma_kernel(const _Float16* __restrict__ pt, const _Float16* __restrict__ pc,
                         float* __restrict__ dotb)
{
    const int b = blockIdx.z >> 2, ks4 = blockIdx.z & 3;
    const _Float16* __restrict__ A  = pt + (size_t)b * L_ * C_ + (ks4 << 7);
    const _Float16* __restrict__ Bm = pc + (size_t)b * L_ * C_ + (ks4 << 7);
    float* __restrict__ D = dotb + (size_t)ks4 * (B_ * L_ * L_) + (size_t)b * (L_ * L_);

    __shared__ _Float16 Ah[2][64][40];
    __shared__ _Float16 Bh[2][64][40];

    const int tid = threadIdx.x;
    const int m0 = blockIdx.y << 6, n0 = blockIdx.x << 6;
    const int srow = tid >> 2, sch = (tid & 3) << 3;
    const int lane = tid & 63, wv = tid >> 6;
    const int l15 = lane & 15, quad = lane >> 4;

    const _Float16* Ag = A  + (size_t)(m0 + srow) * C_ + sch;
    const _Float16* Bg = Bm + (size_t)(n0 + srow) * C_ + sch;

    half8 av = *(const half8*)Ag;
    half8 bv = *(const half8*)Bg;
    *(half8*)&Ah[0][srow][sch] = av;
    *(half8*)&Bh[0][srow][sch] = bv;

    f32x4 acc[4] = {};
    for (int t = 0; t < 4; ++t) {
        const int cur = t & 1;
        if (t < 3) {
            Ag += 32; Bg += 32;
            av = *(const half8*)Ag;
            bv = *(const half8*)Bg;
        }
        __syncthreads();
        half8 af = *(const half8*)&Ah[cur][(wv << 4) + l15][quad << 3];
        #pragma unroll
        for (int nb = 0; nb < 4; ++nb) {
            half8 bf = *(const half8*)&Bh[cur][(nb << 4) + l15][quad << 3];
            acc[nb] = __builtin_amdgcn_mfma_f32_16x16x32_f16(af, bf, acc[nb], 0, 0, 0);
        }
        if (t < 3) {
            *(half8*)&Ah[cur ^ 1][srow][sch] = av;
            *(half8*)&Bh[cur ^ 1][srow][sch] = bv;
        }
    }
    #pragma unroll
    for (int nb = 0; nb < 4; ++nb)
        #pragma unroll
        for (int r = 0; r < 4; ++r)
            D[(size_t)(m0 + (wv << 4) + (quad << 2) + r) * L_ + n0 + (nb << 4) + l15] = acc[nb][r];
}

// ---------------------------------------------------------------------------
// Kernel 2b: scores = sigmoid(sum of 4 dot splits) into dot0 + per-block sums.
// ---------------------------------------------------------------------------
__global__ __launch_bounds__(256)
void sc_finish_kernel(float* __restrict__ dotb, float* __restrict__ sums_part)
{
    __shared__ float red[256];
    const int bl = blockIdx.x;
    const int b  = bl >> 6;
    const size_t off = (size_t)b * (L_ * L_) + (size_t)((bl & 63) << 10) + ((size_t)threadIdx.x << 2);
    float4 d = *(const float4*)&dotb[off];
    #pragma unroll
    for (int k = 1; k < 4; ++k) {
        float4 e = *(const float4*)&dotb[(size_t)k * (B_ * L_ * L_) + off];
        d.x += e.x; d.y += e.y; d.z += e.z; d.w += e.w;
    }
    float4 s;
    s.x = 1.0f / (1.0f + expf(-d.x));
    s.y = 1.0f / (1.0f + expf(-d.y));
    s.z = 1.0f / (1.0f + expf(-d.z));
    s.w = 1.0f / (1.0f + expf(-d.w));
    *(float4*)&dotb[off] = s;
    red[threadIdx.x] = (s.x + s.y) + (s.z + s.w);
    __syncthreads();
    for (int st = 128; st > 0; st >>= 1) {
        if (threadIdx.x < st) red[threadIdx.x] += red[threadIdx.x + st];
        __syncthreads();
    }
    if (threadIdx.x == 0) sums_part[bl] = red[0];
}

// ---------------------------------------------------------------------------
// Kernel 3: partial[b][p][c] = sum_{32i x 16j tile} w[i,j] * r(xd[i,c]*xt[j,c])
// where r = 1/(1+exp2(2*log2e*x)).  (tanh = 1-2r; the wsum term is recovered
// algebraically in finalize: sum w*tanh = S_total - 2*sum(w*r).)
// grid (8,16,16=b*2+chalf) = 2048 blocks. No block reduction, 1 barrier.
// ---------------------------------------------------------------------------
__device__ __forceinline__ float sig2r(float a) {
    float e = __builtin_amdgcn_exp2f(a);
    return __builtin_amdgcn_rcpf(e + 1.0f);
}

__global__ __launch_bounds__(256, 4)
void cp_partial_kernel(const float* __restrict__ xd, const float* __restrict__ xt,
                       const float* __restrict__ scores, float* __restrict__ partials)
{
    const int i0  = blockIdx.x << 5;
    const int j0  = blockIdx.y << 4;
    const int b   = blockIdx.z >> 1;
    const int tid = threadIdx.x;
    const int c   = ((blockIdx.z & 1) << 8) | tid;

    __shared__ float ws_[16][36];   // [jj][ii]; stride 36 floats = 144B (16B-aligned rows)

    const float* __restrict__ sb = scores + (size_t)b * L_ * L_;
    {
        const int jj = tid & 15;
        const int ib = (tid >> 4) << 1;
        #pragma unroll
        for (int r = 0; r < 2; ++r)
            ws_[jj][ib + r] = sb[(size_t)(i0 + ib + r) * L_ + j0 + jj];
    }

    float xds[32], xtv[16];
    const float* __restrict__ xdb = xd + ((size_t)(b * L_ + i0)) * C_ + c;
    const float* __restrict__ xtb = xt + ((size_t)(b * L_ + j0)) * C_ + c;
    #pragma unroll
    for (int i = 0; i < 32; ++i)
        xds[i] = xdb[(size_t)i * C_] * 2.8853900817779268f;   // 2*log2(e)
    #pragma unroll
    for (int j = 0; j < 16; ++j)
        xtv[j] = xtb[(size_t)j * C_];
    __syncthreads();

    float a0 = 0.f, a1 = 0.f, a2 = 0.f, a3 = 0.f;
    #pragma unroll 2
    for (int jj = 0; jj < 16; ++jj) {
        const float xv = xtv[jj];
        #pragma unroll
        for (int i = 0; i < 32; i += 4) {
            const float4 w4 = *(const float4*)&ws_[jj][i];   // wave-uniform broadcast
            a0 = fmaf(w4.x, sig2r(xds[i + 0] * xv), a0);
            a1 = fmaf(w4.y, sig2r(xds[i + 1] * xv), a1);
            a2 = fmaf(w4.z, sig2r(xds[i + 2] * xv), a2);
            a3 = fmaf(w4.w, sig2r(xds[i + 3] * xv), a3);
        }
    }
    const int p = ((int)blockIdx.x << 4) | (int)blockIdx.y;   // 0..127
    partials[(size_t)((b << 7) | p) * C_ + c] = (a0 + a1) + (a2 + a3);
}

// ---------------------------------------------------------------------------
// Kernel 4: S = sum(scores);  cp[b,c] = 1 - 2*(sum_p partial)/S;
//           out = cp @ Wf + bf.  grid (8,8), 512 thr.
// ---------------------------------------------------------------------------
__global__ __launch_bounds__(512)
void finalize_kernel(const float* __restrict__ partials, const float* __restrict__ sums_part,
                     const float* __restrict__ Wf, const float* __restrict__ bfv,
                     float* __restrict__ out)
{
    const int b = blockIdx.y;
    const int t = threadIdx.x;
    __shared__ float cp[C_];
    __shared__ float red[512];
    __shared__ float sumsh;

    red[t] = (t < 64) ? sums_part[(b << 6) | t] : 0.f;

    float s = 0.f;
    #pragma unroll
    for (int p = 0; p < 128; ++p)
        s += partials[(size_t)((b << 7) | p) * C_ + t];

    __syncthreads();
    for (int st = 256; st > 0; st >>= 1) {
        if (t < st) red[t] += red[t + st];
        __syncthreads();
    }
    if (t == 0) sumsh = red[0];
    __syncthreads();

    cp[t] = 1.0f - 2.0f * s / sumsh;
    __syncthreads();

    const int o  = ((int)blockIdx.x << 6) | (t & 63);
    const int c0 = (t >> 6) << 6;
    float acc = 0.f;
    #pragma unroll 8
    for (int i = 0; i < 64; ++i) {
        const int cc = c0 + i;
        acc = fmaf(cp[cc], Wf[(size_t)cc * OUT_ + o], acc);
    }
    red[t] = acc;
    __syncthreads();
    if (t < 64) {
        float a = 0.f;
        #pragma unroll
        for (int g = 0; g < 8; ++g) a += red[(g << 6) | t];
        out[(size_t)b * OUT_ + o] = a + bfv[o];
    }
}

// ---------------------------------------------------------------------------
extern "C" void kernel_launch(void* const* d_in, const int* in_sizes, int n_in,
                              void* d_out, int out_size, void* d_ws, size_t ws_size,
                              hipStream_t stream)
{
    const float* xd = (const float*)d_in[0];
    const float* xt = (const float*)d_in[1];
    const float* Wc = (const float*)d_in[2];
    const float* bc = (const float*)d_in[3];
    const float* Wp = (const float*)d_in[4];
    const float* bp = (const float*)d_in[5];
    const float* Wf = (const float*)d_in[6];
    const float* bf = (const float*)d_in[7];
    float* out = (float*)d_out;

    // workspace layout (~13 MB). partials aliases pt (dead after sc_gemm;
    // stream ordering makes the reuse safe).
    _Float16* hWp = (_Float16*)d_ws;                 // 512 KB
    _Float16* hWc = hWp + 262144;                    // 512 KB
    _Float16* pt  = hWc + 262144;                    // 2 MB
    _Float16* pc  = pt + 1048576;                    // 2 MB
    float* dotb      = (float*)(pc + 1048576);       // 4 x 2 MB (dot0 -> scores)
    float* sums_part = dotb + 4 * (B_ * L_ * L_);    // 512 floats
    float* partials  = (float*)pt;                   // 2 MB (aliased)

    wconv_kernel<<<dim3(16, 16, 2), 256, 0, stream>>>(Wp, Wc, hWp, hWc);
    proj_mfma_kernel<<<dim3(8, 32, 2), 256, 0, stream>>>(xt, hWp, bp, xd, hWc, bc, pt, pc);
    sc_gemm_mfma_kernel<<<dim3(4, 4, 32), 256, 0, stream>>>(pt, pc, dotb);
    sc_finish_kernel<<<512, 256, 0, stream>>>(dotb, sums_part);
    cp_partial_kernel<<<dim3(8, 16, 16), 256, 0, stream>>>(xd, xt, dotb, partials);
    finalize_kernel<<<dim3(8, 8), 512, 0, stream>>>(partials, sums_part, Wf, bf, out);
}

// Round 6
// 147.936 us; speedup vs baseline: 1.4474x; 1.0400x over previous
//
#include <hip/hip_runtime.h>
#include <math.h>

// Problem constants
#define B_   8
#define L_   256
#define C_   512
#define OUT_ 512

typedef _Float16 half8 __attribute__((ext_vector_type(8)));
typedef _Float16 half4 __attribute__((ext_vector_type(4)));
typedef float    f32x4 __attribute__((ext_vector_type(4)));

// ---------------------------------------------------------------------------
// Kernel 0: weight convert+transpose: hW[n][k] = (f16) W[k][n], for Wp and Wc.
// ---------------------------------------------------------------------------
__global__ __launch_bounds__(256)
void wconv_kernel(const float* __restrict__ Wp, const float* __restrict__ Wc,
                  _Float16* __restrict__ hWp, _Float16* __restrict__ hWc)
{
    const int which = blockIdx.z;
    const float* __restrict__ W = which ? Wc : Wp;
    _Float16* __restrict__ H    = which ? hWc : hWp;
    __shared__ float tl[32][33];
    const int k0 = blockIdx.y << 5, n0 = blockIdx.x << 5;
    const int tr = threadIdx.x >> 5, tc = threadIdx.x & 31;
    #pragma unroll
    for (int i = 0; i < 32; i += 8)
        tl[tr + i][tc] = W[(size_t)(k0 + tr + i) * C_ + n0 + tc];
    __syncthreads();
    #pragma unroll
    for (int i = 0; i < 32; i += 8)
        H[(size_t)(n0 + tr + i) * C_ + k0 + tc] = (_Float16)tl[tc][tr + i];
}

// ---------------------------------------------------------------------------
// Kernel 1: MFMA relu-GEMM projections (f16 in, f32 acc, f16 out).
// 64x64 tile, K-step 32, double-buffered LDS, 1 barrier/step. grid (8,32,2).
// ---------------------------------------------------------------------------
__global__ __launch_bounds__(256)
void proj_mfma_kernel(const float* __restrict__ xt, const _Float16* __restrict__ hWp,
                      const float* __restrict__ bp,
                      const float* __restrict__ xd, const _Float16* __restrict__ hWc,
                      const float* __restrict__ bc,
                      _Float16* __restrict__ pt, _Float16* __restrict__ pc)
{
    const int which = blockIdx.z;
    const float*    __restrict__ X    = which ? xd : xt;
    const _Float16* __restrict__ W    = which ? hWc : hWp;
    const float*    __restrict__ bias = which ? bc : bp;
    _Float16*       __restrict__ Y    = which ? pc : pt;

    __shared__ _Float16 Ah[2][64][40];
    __shared__ _Float16 Bh[2][64][40];
    __shared__ _Float16 Ot[64][72];

    const int tid = threadIdx.x;
    const int m0 = blockIdx.y << 6, n0 = blockIdx.x << 6;
    const int srow = tid >> 2, sch = (tid & 3) << 3;
    const int lane = tid & 63, wv = tid >> 6;
    const int l15 = lane & 15, quad = lane >> 4;

    const float*    Ag = X + (size_t)(m0 + srow) * C_ + sch;
    const _Float16* Bg = W + (size_t)(n0 + srow) * C_ + sch;

    float4 a0 = *(const float4*)(Ag);
    float4 a1 = *(const float4*)(Ag + 4);
    half8  bv = *(const half8*)(Bg);

    {
        half8 av;
        av[0] = (_Float16)fmaxf(a0.x, 0.f); av[1] = (_Float16)fmaxf(a0.y, 0.f);
        av[2] = (_Float16)fmaxf(a0.z, 0.f); av[3] = (_Float16)fmaxf(a0.w, 0.f);
        av[4] = (_Float16)fmaxf(a1.x, 0.f); av[5] = (_Float16)fmaxf(a1.y, 0.f);
        av[6] = (_Float16)fmaxf(a1.z, 0.f); av[7] = (_Float16)fmaxf(a1.w, 0.f);
        *(half8*)&Ah[0][srow][sch] = av;
        *(half8*)&Bh[0][srow][sch] = bv;
    }

    f32x4 acc[4] = {};
    for (int ks = 0; ks < 16; ++ks) {
        const int cur = ks & 1;
        if (ks < 15) {
            Ag += 32; Bg += 32;
            a0 = *(const float4*)(Ag);
            a1 = *(const float4*)(Ag + 4);
            bv = *(const half8*)(Bg);
        }
        __syncthreads();
        half8 af = *(const half8*)&Ah[cur][(wv << 4) + l15][quad << 3];
        #pragma unroll
        for (int nb = 0; nb < 4; ++nb) {
            half8 bf = *(const half8*)&Bh[cur][(nb << 4) + l15][quad << 3];
            acc[nb] = __builtin_amdgcn_mfma_f32_16x16x32_f16(af, bf, acc[nb], 0, 0, 0);
        }
        if (ks < 15) {
            half8 av;
            av[0] = (_Float16)fmaxf(a0.x, 0.f); av[1] = (_Float16)fmaxf(a0.y, 0.f);
            av[2] = (_Float16)fmaxf(a0.z, 0.f); av[3] = (_Float16)fmaxf(a0.w, 0.f);
            av[4] = (_Float16)fmaxf(a1.x, 0.f); av[5] = (_Float16)fmaxf(a1.y, 0.f);
            av[6] = (_Float16)fmaxf(a1.z, 0.f); av[7] = (_Float16)fmaxf(a1.w, 0.f);
            *(half8*)&Ah[cur ^ 1][srow][sch] = av;
            *(half8*)&Bh[cur ^ 1][srow][sch] = bv;
        }
    }

    __syncthreads();
    #pragma unroll
    for (int nb = 0; nb < 4; ++nb) {
        const float bz = bias[n0 + (nb << 4) + l15];
        #pragma unroll
        for (int r = 0; r < 4; ++r)
            Ot[(wv << 4) + (quad << 2) + r][(nb << 4) + l15] = (_Float16)(acc[nb][r] + bz);
    }
    __syncthreads();
    const int erow = tid >> 3, ech = (tid & 7) << 3;
    #pragma unroll
    for (int h = 0; h < 64; h += 32)
        *(half8*)&Y[(size_t)(m0 + erow + h) * C_ + n0 + ech] = *(const half8*)&Ot[erow + h][ech];
}

// ---------------------------------------------------------------------------
// Kernel 2 (FUSED): per (i-tile 32, j-tile 32, b):
//  phase 1: dot[i][j] = sum_c pt.pc via MFMA (K=512, dbuf), sigmoid -> ws_ LDS
//           + per-block score sum -> sums_part
//  phase 2: partial[b][p][c] = sum_{i,j} ws_[j][i] * r(xd[i,c]*xt[j,c]),
//           r = 1/(1+exp2(2*log2e*x)); pairwise rcp (1 rcp per 2 elems).
//  (tanh = 1-2r; finalize recovers: sum w*tanh = S - 2*sum(w*r).)
// grid (8,8,8) = 512 blocks x 512 threads (phase2: thread = channel).
// ---------------------------------------------------------------------------
__device__ __forceinline__ float sigmoid_fast(float z) {
    // 1/(1+2^(-z*log2e))
    float e = __builtin_amdgcn_exp2f(-1.4426950408889634f * z);
    return __builtin_amdgcn_rcpf(e + 1.0f);
}

__global__ __launch_bounds__(512, 4)
void cp_scores_kernel(const _Float16* __restrict__ pt, const _Float16* __restrict__ pc,
                      const float* __restrict__ xd, const float* __restrict__ xt,
                      float* __restrict__ partials, float* __restrict__ sums_part)
{
    const int bx = blockIdx.x, by = blockIdx.y, b = blockIdx.z;
    const int i0 = bx << 5, j0 = by << 5;
    const int tid = threadIdx.x;
    const int lane = tid & 63, wv = tid >> 6;
    const int l15 = lane & 15, quad = lane >> 4;

    __shared__ _Float16 Ah[2][32][40];
    __shared__ _Float16 Bh[2][32][40];
    __shared__ float ws_[32][36];     // [j][i]
    __shared__ float wred[4];

    // ---- phase 1: 32x32 dot tile, MFMA, dbuf ----
    // staging: threads 0-255 -> A (pt rows i0..), 256-511 -> B (pc rows j0..)
    const int sHalf = tid >> 8;
    const int srow  = (tid & 255) >> 3;   // 0..31
    const int sch   = (tid & 7) << 2;     // 0,4,...,28
    const _Float16* Sg = (sHalf ? pc + (size_t)(b * L_ + j0 + srow) * C_
                                : pt + (size_t)(b * L_ + i0 + srow) * C_) + sch;

    half4 v = *(const half4*)Sg;
    if (sHalf) *(half4*)&Bh[0][srow][sch] = v; else *(half4*)&Ah[0][srow][sch] = v;

    f32x4 acc = {};
    for (int ks = 0; ks < 16; ++ks) {
        const int cur = ks & 1;
        if (ks < 15) { Sg += 32; v = *(const half4*)Sg; }
        __syncthreads();
        if (wv < 4) {   // waves 0-3 own the 4 16x16 quadrants; 4-7 stage only
            half8 af = *(const half8*)&Ah[cur][((wv >> 1) << 4) + l15][quad << 3];
            half8 bf = *(const half8*)&Bh[cur][((wv & 1) << 4) + l15][quad << 3];
            acc = __builtin_amdgcn_mfma_f32_16x16x32_f16(af, bf, acc, 0, 0, 0);
        }
        if (ks < 15) {
            if (sHalf) *(half4*)&Bh[cur ^ 1][srow][sch] = v;
            else       *(half4*)&Ah[cur ^ 1][srow][sch] = v;
        }
    }

    float lsum = 0.f;
    if (wv < 4) {
        const int n = ((wv & 1) << 4) + l15;            // j index (MFMA col)
        const int m = ((wv >> 1) << 4) + (quad << 2);   // i index (MFMA row base)
        float4 sg;
        sg.x = sigmoid_fast(acc[0]);
        sg.y = sigmoid_fast(acc[1]);
        sg.z = sigmoid_fast(acc[2]);
        sg.w = sigmoid_fast(acc[3]);
        *(float4*)&ws_[n][m] = sg;                      // row stride 144B, 16B-aligned
        lsum = (sg.x + sg.y) + (sg.z + sg.w);
    }
    #pragma unroll
    for (int off = 32; off; off >>= 1) lsum += __shfl_xor(lsum, off);
    if (wv < 4 && lane == 0) wred[wv] = lsum;
    __syncthreads();                                    // ws_ + wred ready
    if (tid == 0)
        sums_part[(b << 6) | (bx << 3) | by] = (wred[0] + wred[1]) + (wred[2] + wred[3]);

    // ---- phase 2: weighted tanh-r accumulation, thread = channel ----
    const int c = tid;
    const float* __restrict__ xdb = xd + (size_t)(b * L_ + i0) * C_ + c;
    const float* __restrict__ xtb = xt + (size_t)(b * L_ + j0) * C_ + c;
    float xds[32], xtv[32];
    #pragma unroll
    for (int i = 0; i < 32; ++i)
        xds[i] = xdb[(size_t)i * C_] * 2.8853900817779268f;   // 2*log2(e)
    #pragma unroll
    for (int j = 0; j < 32; ++j)
        xtv[j] = xtb[(size_t)j * C_];

    float a0 = 0.f, a1 = 0.f, a2 = 0.f, a3 = 0.f;
    for (int jj = 0; jj < 32; ++jj) {
        const float xv = xtv[jj];
        #pragma unroll
        for (int i = 0; i < 32; i += 4) {
            const float4 w4 = *(const float4*)&ws_[jj][i];   // wave-uniform broadcast
            // pair (i, i+1): one rcp for two sigmoids
            float e0 = __builtin_amdgcn_exp2f(xds[i + 0] * xv);
            float e1 = __builtin_amdgcn_exp2f(xds[i + 1] * xv);
            float q0 = e0 + 1.0f, q1 = e1 + 1.0f;
            float rp01 = __builtin_amdgcn_rcpf(q0 * q1);
            a0 = fmaf(w4.x, rp01 * q1, a0);
            a1 = fmaf(w4.y, rp01 * q0, a1);
            // pair (i+2, i+3)
            float e2 = __builtin_amdgcn_exp2f(xds[i + 2] * xv);
            float e3 = __builtin_amdgcn_exp2f(xds[i + 3] * xv);
            float q2 = e2 + 1.0f, q3 = e3 + 1.0f;
            float rp23 = __builtin_amdgcn_rcpf(q2 * q3);
            a2 = fmaf(w4.z, rp23 * q3, a2);
            a3 = fmaf(w4.w, rp23 * q2, a3);
        }
    }
    const int p = (bx << 3) | by;   // 0..63
    partials[(size_t)((b << 6) | p) * C_ + c] = (a0 + a1) + (a2 + a3);
}

// ---------------------------------------------------------------------------
// Kernel 3: S = sum(scores); cp[b,c] = 1 - 2*(sum_p partial)/S; out = cp@Wf+bf
// grid (8,8), 512 thr. p = 64 now.
// ---------------------------------------------------------------------------
__global__ __launch_bounds__(512)
void finalize_kernel(const float* __restrict__ partials, const float* __restrict__ sums_part,
                     const float* __restrict__ Wf, const float* __restrict__ bfv,
                     float* __restrict__ out)
{
    const int b = blockIdx.y;
    const int t = threadIdx.x;
    __shared__ float cp[C_];
    __shared__ float red[512];
    __shared__ float sumsh;

    red[t] = (t < 64) ? sums_part[(b << 6) | t] : 0.f;

    float s = 0.f;
    #pragma unroll
    for (int p = 0; p < 64; ++p)
        s += partials[(size_t)((b << 6) | p) * C_ + t];

    __syncthreads();
    for (int st = 256; st > 0; st >>= 1) {
        if (t < st) red[t] += red[t + st];
        __syncthreads();
    }
    if (t == 0) sumsh = red[0];
    __syncthreads();

    cp[t] = 1.0f - 2.0f * s / sumsh;
    __syncthreads();

    const int o  = ((int)blockIdx.x << 6) | (t & 63);
    const int c0 = (t >> 6) << 6;
    float acc = 0.f;
    #pragma unroll 8
    for (int i = 0; i < 64; ++i) {
        const int cc = c0 + i;
        acc = fmaf(cp[cc], Wf[(size_t)cc * OUT_ + o], acc);
    }
    red[t] = acc;
    __syncthreads();
    if (t < 64) {
        float a = 0.f;
        #pragma unroll
        for (int g = 0; g < 8; ++g) a += red[(g << 6) | t];
        out[(size_t)b * OUT_ + o] = a + bfv[o];
    }
}

// ---------------------------------------------------------------------------
extern "C" void kernel_launch(void* const* d_in, const int* in_sizes, int n_in,
                              void* d_out, int out_size, void* d_ws, size_t ws_size,
                              hipStream_t stream)
{
    const float* xd = (const float*)d_in[0];
    const float* xt = (const float*)d_in[1];
    const float* Wc = (const float*)d_in[2];
    const float* bc = (const float*)d_in[3];
    const float* Wp = (const float*)d_in[4];
    const float* bp = (const float*)d_in[5];
    const float* Wf = (const float*)d_in[6];
    const float* bf = (const float*)d_in[7];
    float* out = (float*)d_out;

    // workspace (~6.1 MB)
    _Float16* hWp = (_Float16*)d_ws;                 // 512 KB
    _Float16* hWc = hWp + 262144;                    // 512 KB
    _Float16* pt  = hWc + 262144;                    // 2 MB
    _Float16* pc  = pt + 1048576;                    // 2 MB
    float* partials  = (float*)(pc + 1048576);       // 8*64*512 fl = 1 MB
    float* sums_part = partials + B_ * 64 * C_;      // 512 fl

    wconv_kernel<<<dim3(16, 16, 2), 256, 0, stream>>>(Wp, Wc, hWp, hWc);
    proj_mfma_kernel<<<dim3(8, 32, 2), 256, 0, stream>>>(xt, hWp, bp, xd, hWc, bc, pt, pc);
    cp_scores_kernel<<<dim3(8, 8, 8), 512, 0, stream>>>(pt, pc, xd, xt, partials, sums_part);
    finalize_kernel<<<dim3(8, 8), 512, 0, stream>>>(partials, sums_part, Wf, bf, out);
}

// Round 7
// 139.276 us; speedup vs baseline: 1.5374x; 1.0622x over previous
//
#include <hip/hip_runtime.h>
#include <math.h>

// Problem constants
#define B_   8
#define L_   256
#define C_   512
#define OUT_ 512

typedef _Float16 half8 __attribute__((ext_vector_type(8)));
typedef _Float16 half4 __attribute__((ext_vector_type(4)));
typedef float    f32x4 __attribute__((ext_vector_type(4)));
typedef float    f32x2 __attribute__((ext_vector_type(2)));

// ---------------------------------------------------------------------------
// Kernel 1: MFMA relu-GEMM projections (f32 in, f16 frags, f32 acc, f16 out).
//   Y[m][n] = sum_k relu(X[m][k]) * W[k][n] + bias[n],  W raw f32 [k][n].
// W transpose+cvt folded into B-staging (8 coalesced row reads / thread /
// step -> half8 [n][k] LDS write). 64x64 tile, KT=32, dbuf, 1 barrier/step.
// grid (8,32,2), 256 thr.
// ---------------------------------------------------------------------------
__global__ __launch_bounds__(256)
void proj_mfma_kernel(const float* __restrict__ xt, const float* __restrict__ Wp,
                      const float* __restrict__ bp,
                      const float* __restrict__ xd, const float* __restrict__ Wc,
                      const float* __restrict__ bc,
                      _Float16* __restrict__ pt, _Float16* __restrict__ pc)
{
    const int which = blockIdx.z;
    const float* __restrict__ X    = which ? xd : xt;
    const float* __restrict__ W    = which ? Wc : Wp;
    const float* __restrict__ bias = which ? bc : bp;
    _Float16*    __restrict__ Y    = which ? pc : pt;

    __shared__ _Float16 Ah[2][64][40];   // [buf][m][k]
    __shared__ _Float16 Bh[2][64][40];   // [buf][n][k]
    __shared__ _Float16 Ot[64][72];

    const int tid = threadIdx.x;
    const int m0 = blockIdx.y << 6, n0 = blockIdx.x << 6;
    const int lane = tid & 63, wv = tid >> 6;
    const int l15 = lane & 15, quad = lane >> 4;

    // A staging: srow 0..63, 8 k's
    const int srow = tid >> 2, sch = (tid & 3) << 3;
    const float* Ag = X + (size_t)(m0 + srow) * C_ + sch;
    // B staging: nl 0..63 (lane), kseg 0..3 (wave): 8 rows of W, one col each
    const int nl = tid & 63, kseg = tid >> 6;
    const float* Bg = W + (size_t)(kseg << 3) * C_ + n0 + nl;

    float4 a0 = *(const float4*)(Ag);
    float4 a1 = *(const float4*)(Ag + 4);
    float wr[8];
    #pragma unroll
    for (int r = 0; r < 8; ++r) wr[r] = Bg[(size_t)r * C_];

    // write buffer 0
    {
        half8 av;
        av[0] = (_Float16)fmaxf(a0.x, 0.f); av[1] = (_Float16)fmaxf(a0.y, 0.f);
        av[2] = (_Float16)fmaxf(a0.z, 0.f); av[3] = (_Float16)fmaxf(a0.w, 0.f);
        av[4] = (_Float16)fmaxf(a1.x, 0.f); av[5] = (_Float16)fmaxf(a1.y, 0.f);
        av[6] = (_Float16)fmaxf(a1.z, 0.f); av[7] = (_Float16)fmaxf(a1.w, 0.f);
        *(half8*)&Ah[0][srow][sch] = av;
        half8 bv;
        #pragma unroll
        for (int r = 0; r < 8; ++r) bv[r] = (_Float16)wr[r];
        *(half8*)&Bh[0][nl][kseg << 3] = bv;
    }

    f32x4 acc[4] = {};
    for (int ks = 0; ks < 16; ++ks) {
        const int cur = ks & 1;
        if (ks < 15) {                        // prefetch next K-slab into regs
            Ag += 32;
            Bg += 32 * C_;
            a0 = *(const float4*)(Ag);
            a1 = *(const float4*)(Ag + 4);
            #pragma unroll
            for (int r = 0; r < 8; ++r) wr[r] = Bg[(size_t)r * C_];
        }
        __syncthreads();
        half8 af = *(const half8*)&Ah[cur][(wv << 4) + l15][quad << 3];
        #pragma unroll
        for (int nb = 0; nb < 4; ++nb) {
            half8 bf = *(const half8*)&Bh[cur][(nb << 4) + l15][quad << 3];
            acc[nb] = __builtin_amdgcn_mfma_f32_16x16x32_f16(af, bf, acc[nb], 0, 0, 0);
        }
        if (ks < 15) {
            half8 av;
            av[0] = (_Float16)fmaxf(a0.x, 0.f); av[1] = (_Float16)fmaxf(a0.y, 0.f);
            av[2] = (_Float16)fmaxf(a0.z, 0.f); av[3] = (_Float16)fmaxf(a0.w, 0.f);
            av[4] = (_Float16)fmaxf(a1.x, 0.f); av[5] = (_Float16)fmaxf(a1.y, 0.f);
            av[6] = (_Float16)fmaxf(a1.z, 0.f); av[7] = (_Float16)fmaxf(a1.w, 0.f);
            *(half8*)&Ah[cur ^ 1][srow][sch] = av;
            half8 bv;
            #pragma unroll
            for (int r = 0; r < 8; ++r) bv[r] = (_Float16)wr[r];
            *(half8*)&Bh[cur ^ 1][nl][kseg << 3] = bv;
        }
    }

    __syncthreads();
    #pragma unroll
    for (int nb = 0; nb < 4; ++nb) {
        const float bz = bias[n0 + (nb << 4) + l15];
        #pragma unroll
        for (int r = 0; r < 4; ++r)
            Ot[(wv << 4) + (quad << 2) + r][(nb << 4) + l15] = (_Float16)(acc[nb][r] + bz);
    }
    __syncthreads();
    const int erow = tid >> 3, ech = (tid & 7) << 3;
    #pragma unroll
    for (int h = 0; h < 64; h += 32)
        *(half8*)&Y[(size_t)(m0 + erow + h) * C_ + n0 + ech] = *(const half8*)&Ot[erow + h][ech];
}

// ---------------------------------------------------------------------------
// Kernel 2 (FUSED): per (i-tile 32, j-tile 32, b):
//  phase 1: dot[i][j] = sum_c pt.pc via MFMA (K=512, dbuf), sigmoid -> ws_ LDS
//           + per-block score sum -> sums_part
//  phase 2: partial[b][p][c] = sum_{i,j} ws_[j][i] * r(xd[i,c]*xt[j,c]),
//           r = 1/(1+exp2(2*log2e*x)); packed f32 (v_pk_*) + 1 rcp / 2 elems.
//  (tanh = 1-2r; finalize recovers: sum w*tanh = S - 2*sum(w*r).)
// grid (8,8,8) = 512 blocks x 512 threads (phase2: thread = channel).
// ---------------------------------------------------------------------------
__device__ __forceinline__ float sigmoid_fast(float z) {
    float e = __builtin_amdgcn_exp2f(-1.4426950408889634f * z);
    return __builtin_amdgcn_rcpf(e + 1.0f);
}

__global__ __launch_bounds__(512, 4)
void cp_scores_kernel(const _Float16* __restrict__ pt, const _Float16* __restrict__ pc,
                      const float* __restrict__ xd, const float* __restrict__ xt,
                      float* __restrict__ partials, float* __restrict__ sums_part)
{
    const int bx = blockIdx.x, by = blockIdx.y, b = blockIdx.z;
    const int i0 = bx << 5, j0 = by << 5;
    const int tid = threadIdx.x;
    const int lane = tid & 63, wv = tid >> 6;
    const int l15 = lane & 15, quad = lane >> 4;

    __shared__ _Float16 Ah[2][32][40];
    __shared__ _Float16 Bh[2][32][40];
    __shared__ float ws_[32][36];     // [j][i]
    __shared__ float wred[4];

    // ---- phase 1: 32x32 dot tile, MFMA, dbuf ----
    const int sHalf = tid >> 8;
    const int srow  = (tid & 255) >> 3;   // 0..31
    const int sch   = (tid & 7) << 2;     // 0,4,...,28
    const _Float16* Sg = (sHalf ? pc + (size_t)(b * L_ + j0 + srow) * C_
                                : pt + (size_t)(b * L_ + i0 + srow) * C_) + sch;

    half4 v = *(const half4*)Sg;
    if (sHalf) *(half4*)&Bh[0][srow][sch] = v; else *(half4*)&Ah[0][srow][sch] = v;

    f32x4 acc = {};
    for (int ks = 0; ks < 16; ++ks) {
        const int cur = ks & 1;
        if (ks < 15) { Sg += 32; v = *(const half4*)Sg; }
        __syncthreads();
        if (wv < 4) {   // waves 0-3 own the 4 16x16 quadrants; 4-7 stage only
            half8 af = *(const half8*)&Ah[cur][((wv >> 1) << 4) + l15][quad << 3];
            half8 bf = *(const half8*)&Bh[cur][((wv & 1) << 4) + l15][quad << 3];
            acc = __builtin_amdgcn_mfma_f32_16x16x32_f16(af, bf, acc, 0, 0, 0);
        }
        if (ks < 15) {
            if (sHalf) *(half4*)&Bh[cur ^ 1][srow][sch] = v;
            else       *(half4*)&Ah[cur ^ 1][srow][sch] = v;
        }
    }

    float lsum = 0.f;
    if (wv < 4) {
        const int n = ((wv & 1) << 4) + l15;            // j index (MFMA col)
        const int m = ((wv >> 1) << 4) + (quad << 2);   // i index (MFMA row base)
        float4 sg;
        sg.x = sigmoid_fast(acc[0]);
        sg.y = sigmoid_fast(acc[1]);
        sg.z = sigmoid_fast(acc[2]);
        sg.w = sigmoid_fast(acc[3]);
        *(float4*)&ws_[n][m] = sg;
        lsum = (sg.x + sg.y) + (sg.z + sg.w);
    }
    #pragma unroll
    for (int off = 32; off; off >>= 1) lsum += __shfl_xor(lsum, off);
    if (wv < 4 && lane == 0) wred[wv] = lsum;
    __syncthreads();                                    // ws_ + wred ready
    if (tid == 0)
        sums_part[(b << 6) | (bx << 3) | by] = (wred[0] + wred[1]) + (wred[2] + wred[3]);

    // ---- phase 2: weighted tanh-r accumulation, thread = channel, pk f32 ----
    const int c = tid;
    const float* __restrict__ xdb = xd + (size_t)(b * L_ + i0) * C_ + c;
    const float* __restrict__ xtb = xt + (size_t)(b * L_ + j0) * C_ + c;
    f32x2 xds2[16];
    float xtv[32];
    #pragma unroll
    for (int i = 0; i < 16; ++i) {
        xds2[i].x = xdb[(size_t)(2 * i) * C_]     * 2.8853900817779268f;  // 2*log2(e)
        xds2[i].y = xdb[(size_t)(2 * i + 1) * C_] * 2.8853900817779268f;
    }
    #pragma unroll
    for (int j = 0; j < 32; ++j)
        xtv[j] = xtb[(size_t)j * C_];

    f32x2 acc01 = {0.f, 0.f}, acc23 = {0.f, 0.f};
    for (int jj = 0; jj < 32; ++jj) {
        const float xv = xtv[jj];
        #pragma unroll
        for (int i = 0; i < 32; i += 4) {
            const float4 w4 = *(const float4*)&ws_[jj][i];   // wave-uniform broadcast
            // pair (i, i+1)
            f32x2 x01 = xds2[i >> 1] * xv;                    // v_pk_mul
            f32x2 e01 = { __builtin_amdgcn_exp2f(x01.x), __builtin_amdgcn_exp2f(x01.y) };
            f32x2 q01 = e01 + 1.0f;                           // v_pk_add
            float rp01 = __builtin_amdgcn_rcpf(q01.x * q01.y);
            f32x2 r01 = rp01 * __builtin_shufflevector(q01, q01, 1, 0);  // v_pk_mul (op_sel)
            f32x2 w01 = { w4.x, w4.y };
            acc01 = w01 * r01 + acc01;                        // v_pk_fma
            // pair (i+2, i+3)
            f32x2 x23 = xds2[(i >> 1) + 1] * xv;
            f32x2 e23 = { __builtin_amdgcn_exp2f(x23.x), __builtin_amdgcn_exp2f(x23.y) };
            f32x2 q23 = e23 + 1.0f;
            float rp23 = __builtin_amdgcn_rcpf(q23.x * q23.y);
            f32x2 r23 = rp23 * __builtin_shufflevector(q23, q23, 1, 0);
            f32x2 w23 = { w4.z, w4.w };
            acc23 = w23 * r23 + acc23;
        }
    }
    const int p = (bx << 3) | by;   // 0..63
    partials[(size_t)((b << 6) | p) * C_ + c] =
        (acc01.x + acc01.y) + (acc23.x + acc23.y);
}

// ---------------------------------------------------------------------------
// Kernel 3: S = sum(scores); cp[b,c] = 1 - 2*(sum_p partial)/S; out = cp@Wf+bf
// grid (8,8), 512 thr.
// ---------------------------------------------------------------------------
__global__ __launch_bounds__(512)
void finalize_kernel(const float* __restrict__ partials, const float* __restrict__ sums_part,
                     const float* __restrict__ Wf, const float* __restrict__ bfv,
                     float* __restrict__ out)
{
    const int b = blockIdx.y;
    const int t = threadIdx.x;
    __shared__ float cp[C_];
    __shared__ float red[512];
    __shared__ float sumsh;

    red[t] = (t < 64) ? sums_part[(b << 6) | t] : 0.f;

    float s = 0.f;
    #pragma unroll
    for (int p = 0; p < 64; ++p)
        s += partials[(size_t)((b << 6) | p) * C_ + t];

    __syncthreads();
    for (int st = 256; st > 0; st >>= 1) {
        if (t < st) red[t] += red[t + st];
        __syncthreads();
    }
    if (t == 0) sumsh = red[0];
    __syncthreads();

    cp[t] = 1.0f - 2.0f * s / sumsh;
    __syncthreads();

    const int o  = ((int)blockIdx.x << 6) | (t & 63);
    const int c0 = (t >> 6) << 6;
    float acc = 0.f;
    #pragma unroll 8
    for (int i = 0; i < 64; ++i) {
        const int cc = c0 + i;
        acc = fmaf(cp[cc], Wf[(size_t)cc * OUT_ + o], acc);
    }
    red[t] = acc;
    __syncthreads();
    if (t < 64) {
        float a = 0.f;
        #pragma unroll
        for (int g = 0; g < 8; ++g) a += red[(g << 6) | t];
        out[(size_t)b * OUT_ + o] = a + bfv[o];
    }
}

// ---------------------------------------------------------------------------
extern "C" void kernel_launch(void* const* d_in, const int* in_sizes, int n_in,
                              void* d_out, int out_size, void* d_ws, size_t ws_size,
                              hipStream_t stream)
{
    const float* xd = (const float*)d_in[0];
    const float* xt = (const float*)d_in[1];
    const float* Wc = (const float*)d_in[2];
    const float* bc = (const float*)d_in[3];
    const float* Wp = (const float*)d_in[4];
    const float* bp = (const float*)d_in[5];
    const float* Wf = (const float*)d_in[6];
    const float* bf = (const float*)d_in[7];
    float* out = (float*)d_out;

    // workspace (~5.1 MB)
    _Float16* pt  = (_Float16*)d_ws;                 // 2 MB
    _Float16* pc  = pt + 1048576;                    // 2 MB
    float* partials  = (float*)(pc + 1048576);       // 8*64*512 fl = 1 MB
    float* sums_part = partials + B_ * 64 * C_;      // 512 fl

    proj_mfma_kernel<<<dim3(8, 32, 2), 256, 0, stream>>>(xt, Wp, bp, xd, Wc, bc, pt, pc);
    cp_scores_kernel<<<dim3(8, 8, 8), 512, 0, stream>>>(pt, pc, xd, xt, partials, sums_part);
    finalize_kernel<<<dim3(8, 8), 512, 0, stream>>>(partials, sums_part, Wf, bf, out);
}